// Round 2
// baseline (285.046 us; speedup 1.0000x reference)
//
#include <hip/hip_runtime.h>
#include <hip/hip_cooperative_groups.h>
#include <math.h>

namespace cg = cooperative_groups;

#define NPART 4096
#define NBLK  512
#define NTHR  256
#define IPB   8     // particles (i) per block

// Constants, rounded exactly as the reference's weak-typed doubles -> f32
constexpr float RORC   = (float)(2.5e-5 + 3.15e-6);    // RO + RC
constexpr float RORC2  = RORC * RORC;
constexpr float RRF    = 8e-6f;                        // RR
constexpr float RR2    = RRF * RRF;
constexpr float TWORC  = (float)(2.0 * 3.15e-6);       // 2*RC
constexpr float TWORC2 = TWORC * TWORC;
constexpr float C21RC  = (float)(2.1 * 3.15e-6);       // 2.1*RC
constexpr float C_ROT  = (float)(0.2 * 25.0 * 0.0028); // dt*Gamma*DR
constexpr float C_RN1  = (float)0.07483314773547883;   // f32(sqrt(2*DR))
constexpr float C_SQDT = (float)0.4472135954999579;    // f32(sqrt(dt))
constexpr float C_TRV  = (float)(0.2 * 5e-7);          // dt*velocity
constexpr float C_HALF = (float)0.7071067811865476;    // f32(sqrt(0.5))
constexpr float C_SQ2T = (float)1.6733200530681511e-07;// f32(sqrt(2*DT_TRANS))
constexpr float EPSF   = 1e-14f;

// ---------------------------------------------------------------------------
// Single cooperative kernel: pair sums + epilogue + 3 collision passes.
// 512 blocks x 256 thr (2 blocks/CU: 69 KB LDS each). Block owns 8 i's;
// 32 j-segments of 128. grid.sync() between collision passes.
// ---------------------------------------------------------------------------
__global__ __launch_bounds__(NTHR) void fused_kernel(
        const float2* __restrict__ pos, const float2* __restrict__ ori,
        const float* __restrict__ Deltas, const float* __restrict__ rot_noise,
        const float2* __restrict__ trans_noise,
        float2* __restrict__ out, float2* __restrict__ pA,
        float2* __restrict__ pB) {
    cg::grid_group grid = cg::this_grid();

    __shared__ float4 pu[NPART];          // 64 KB (aliased float2 in collide)
    __shared__ float  sred[5 * NTHR];     // 5 KB reduction scratch
    __shared__ float  res[5][IPB];

    const int tid  = threadIdx.x;
    const int il   = tid & (IPB - 1);     // i within block
    const int seg  = tid / IPB;           // 0..31
    const int gi   = blockIdx.x * IPB + il;
    const int base = seg * 128;

    // ---- stage pos+ori into LDS ----
    for (int k = 0; k < NPART / NTHR; ++k) {
        const int j = k * NTHR + tid;
        const float2 pj = pos[j];
        const float2 uj = ori[j];
        pu[j] = make_float4(pj.x, pj.y, uj.x, uj.y);
    }
    __syncthreads();

    // ---- pairwise phase: n_r, sum_rr(p), orientation_sums(u) ----
    const float pix = pu[gi].x, piy = pu[gi].y;
    float nr = 0.f, sx = 0.f, sy = 0.f, oxs = 0.f, oys = 0.f;
    #pragma unroll 4
    for (int t = 0; t < 128; ++t) {
        const int j = base + ((t + seg) & 127);   // stagger: distinct banks
        const float4 v = pu[j];
        const float dx = v.x - pix, dy = v.y - piy;
        const float r2 = fmaf(dx, dx, dy * dy);
        const bool oc = (r2 <= RORC2);            // inside_Ro (diag included)
        oxs += oc ? v.z : 0.f;
        oys += oc ? v.w : 0.f;
        if (r2 <= RR2) {                          // rare
            // in_front fails <=> dot<=0 && cross>=0 (diag auto-fails)
            const float dt_ = fmaf(dx, v.z, dy * v.w);
            const float cr_ = fmaf(dy, v.z, -dx * v.w);
            const bool fail = (dt_ <= 0.f) && (cr_ >= 0.f);
            if (r2 > 0.f && !fail) { nr += 1.f; sx += v.x; sy += v.y; }
        }
    }
    __syncthreads();
    sred[0 * NTHR + tid] = nr;
    sred[1 * NTHR + tid] = sx;
    sred[2 * NTHR + tid] = sy;
    sred[3 * NTHR + tid] = oxs;
    sred[4 * NTHR + tid] = oys;
    __syncthreads();
    if (tid < 5 * IPB) {                   // same order as R1 -> bit-identical
        const int q = tid / IPB, ii = tid & (IPB - 1);
        float acc = 0.f;
        #pragma unroll
        for (int s = 0; s < 32; ++s) acc += sred[q * NTHR + ii + IPB * s];
        res[q][ii] = acc;
    }
    __syncthreads();

    // ---- mean of all positions (n_a == N) — same order as R1 epilogue ----
    float mx = 0.f, my = 0.f;
    for (int k = 0; k < NPART / NTHR; ++k) {
        const float4 v = pu[k * NTHR + tid];
        mx += v.x; my += v.y;
    }
    sred[tid] = mx; sred[NTHR + tid] = my;
    __syncthreads();
    for (int s = NTHR / 2; s > 0; s >>= 1) {
        if (tid < s) { sred[tid] += sred[tid + s]; sred[NTHR + tid] += sred[NTHR + tid + s]; }
        __syncthreads();
    }
    const float cmx = sred[0]    * (1.f / NPART);
    const float cmy = sred[NTHR] * (1.f / NPART);

    // ---- per-i epilogue (8 threads) ----
    if (tid < IPB) {
        const int g2 = blockIdx.x * IPB + tid;
        const float2 p = make_float2(pu[g2].x, pu[g2].y);
        const float2 u = make_float2(pu[g2].z, pu[g2].w);
        const float nrv = res[0][tid], sxv = res[1][tid], syv = res[2][tid];
        const float osx = res[3][tid], osy = res[4][tid];

        const float inv = 1.f / fmaxf(nrv, 1.f);
        const float sg  = (nrv > 0.f) ? 1.f : 0.f;
        const float Sx = sxv * inv - p.x * sg;
        const float Sy = syv * inv - p.y * sg;
        const float dxv = -Sx, dyv = -Sy;        // d = -S

        const float Psx = cmx - p.x;
        const float Psy = cmy - p.y;

        float sd, cd;
        sincosf(Deltas[0], &sd, &cd);
        const float Lx = Psx * cd - Psy * sd;    // Ps * exp(+i*Delta)
        const float Ly = Psx * sd + Psy * cd;
        const float Rx = Psx * cd + Psy * sd;    // Ps * exp(-i*Delta)
        const float Ry = Psy * cd - Psx * sd;

        const float no  = fmaxf(sqrtf(osx * osx + osy * osy + 1e-30f), EPSF);
        const float nl  = fmaxf(sqrtf(Lx * Lx + Ly * Ly + 1e-30f), EPSF);
        const float nrr = fmaxf(sqrtf(Rx * Rx + Ry * Ry + 1e-30f), EPSF);
        const float csl = (Lx * osx + Ly * osy) / (nl * no);
        const float csr = (Rx * osx + Ry * osy) / (nrr * no);
        const bool left = (csl >= csr);
        const float bx = left ? Lx : Rx;
        const float by = left ? Ly : Ry;

        float cx, cy;
        if (dxv != 0.f || dyv != 0.f)    { cx = dxv; cy = dyv; }
        else if (bx != 0.f || by != 0.f) { cx = bx;  cy = by;  }
        else                             { cx = 1.f; cy = 0.f; }

        const float dt_ = cx * u.x + cy * u.y;
        const float cr_ = cy * u.x - cx * u.y;
        const float sin_t = cr_ / sqrtf(dt_ * dt_ + cr_ * cr_);

        const float ang = C_ROT * sin_t + (rot_noise[g2] * C_RN1) * C_SQDT;
        float sa, ca;
        sincosf(ang, &sa, &ca);
        const float nux = u.x * ca - u.y * sa;
        const float nuy = u.x * sa + u.y * ca;

        const float2 tn = trans_noise[g2];
        const float tvx = C_TRV * u.x + ((tn.x * C_HALF) * C_SQ2T) * C_SQDT;
        const float tvy = C_TRV * u.y + ((tn.y * C_HALF) * C_SQ2T) * C_SQDT;

        out[1 * NPART + g2] = make_float2(nux, nuy);
        out[2 * NPART + g2] = make_float2(osx, osy);
        out[3 * NPART + g2] = make_float2(Lx, Ly);
        out[4 * NPART + g2] = make_float2(Rx, Ry);
        pA[g2] = make_float2(p.x + tvx, p.y + tvy);
    }
    grid.sync();

    // ---- 3 collision relaxation passes ----
    float2* pl = (float2*)pu;             // 32 KB alias
    const float2* srcs[3] = {pA, pB, pA};
    float2*       dsts[3] = {pB, pA, out};   // last pass -> out section 0

    for (int pass = 0; pass < 3; ++pass) {
        const float2* src = srcs[pass];
        float2*       dst = dsts[pass];

        for (int k = 0; k < NPART / NTHR; ++k) {
            const int j = k * NTHR + tid;
            pl[j] = src[j];
        }
        __syncthreads();

        const float qx = pl[gi].x, qy = pl[gi].y;
        float ax = 0.f, ay = 0.f;
        #pragma unroll 4
        for (int t = 0; t < 128; ++t) {
            const int j = base + ((t + seg) & 127);
            const float2 v = pl[j];
            const float dx = v.x - qx, dy = v.y - qy;
            const float r2 = fmaf(dx, dx, dy * dy);
            if (r2 <= TWORC2 && r2 > 0.f) {
                const float ab = sqrtf(r2);
                const float s = (C21RC - ab) * 0.5f / ab;
                ax = fmaf(dx, s, ax);
                ay = fmaf(dy, s, ay);
            }
        }
        __syncthreads();
        sred[tid] = ax; sred[NTHR + tid] = ay;
        __syncthreads();
        if (tid < 2 * IPB) {
            const int q = tid / IPB, ii = tid & (IPB - 1);
            float acc = 0.f;
            #pragma unroll
            for (int s = 0; s < 32; ++s) acc += sred[q * NTHR + ii + IPB * s];
            res[q][ii] = acc;
        }
        __syncthreads();
        if (tid < IPB) {
            // tid<IPB => seg==0, il==tid: (qx,qy) is particle blockIdx*IPB+tid
            dst[blockIdx.x * IPB + tid] = make_float2(qx - res[0][tid], qy - res[1][tid]);
        }
        if (pass != 2) grid.sync();
    }
}

extern "C" void kernel_launch(void* const* d_in, const int* in_sizes, int n_in,
                              void* d_out, int out_size, void* d_ws, size_t ws_size,
                              hipStream_t stream) {
    const float2* pos = (const float2*)d_in[0];
    const float2* ori = (const float2*)d_in[1];
    const float*  del = (const float*)d_in[2];
    const float*  rn  = (const float*)d_in[3];
    const float2* tn  = (const float2*)d_in[4];

    float2* pA = (float2*)d_ws;
    float2* pB = pA + NPART;
    float2* o2 = (float2*)d_out;          // [5][N] float2

    void* args[] = {(void*)&pos, (void*)&ori, (void*)&del, (void*)&rn,
                    (void*)&tn,  (void*)&o2,  (void*)&pA,  (void*)&pB};
    hipLaunchCooperativeKernel((const void*)fused_kernel, dim3(NBLK), dim3(NTHR),
                               args, 0, stream);
}

// Round 3
// 142.612 us; speedup vs baseline: 1.9987x; 1.9987x over previous
//
#include <hip/hip_runtime.h>
#include <math.h>

#define NPART 4096
#define NBLK  512
#define NTHR  256
#define IPB   8     // particles (i) per block
#define CAP   512   // max candidate pairs per block (expected ~52)

// Constants, rounded exactly as the reference's weak-typed doubles -> f32
constexpr float RORC   = (float)(2.5e-5 + 3.15e-6);    // RO + RC
constexpr float RORC2  = RORC * RORC;
constexpr float RRF    = 8e-6f;                        // RR
constexpr float RR2    = RRF * RRF;
constexpr float TWORC  = (float)(2.0 * 3.15e-6);       // 2*RC
constexpr float TWORC2 = TWORC * TWORC;
constexpr float C21RC  = (float)(2.1 * 3.15e-6);       // 2.1*RC
constexpr float RCAND2 = 1.6e-9f;                      // (4e-5)^2 candidate radius^2
constexpr float C_ROT  = (float)(0.2 * 25.0 * 0.0028); // dt*Gamma*DR
constexpr float C_RN1  = (float)0.07483314773547883;   // f32(sqrt(2*DR))
constexpr float C_SQDT = (float)0.4472135954999579;    // f32(sqrt(dt))
constexpr float C_TRV  = (float)(0.2 * 5e-7);          // dt*velocity
constexpr float C_HALF = (float)0.7071067811865476;    // f32(sqrt(0.5))
constexpr float C_SQ2T = (float)1.6733200530681511e-07;// f32(sqrt(2*DT_TRANS))
constexpr float EPSF   = 1e-14f;

// ---------------------------------------------------------------------------
// Kernel 1: pair sums + per-block mean + epilogue + collision-candidate
// detection. 512 blocks x 256 thr. Block owns 8 i's; 32 j-segments of 128.
// Reduction orders identical to R1 (bit-exact sections 1..4).
// ---------------------------------------------------------------------------
__global__ __launch_bounds__(NTHR) void fused_main(
        const float2* __restrict__ pos, const float2* __restrict__ ori,
        const float* __restrict__ Deltas, const float* __restrict__ rot_noise,
        const float2* __restrict__ trans_noise,
        float2* __restrict__ out, float2* __restrict__ pA,
        int* __restrict__ counts, int* __restrict__ pairs_g) {
    __shared__ float4 pu[NPART];          // 64 KB
    __shared__ float  sred[5 * NTHR];     // 5 KB
    __shared__ float  res[5][IPB];
    __shared__ int    lcnt;
    __shared__ int    lpairs[CAP];        // 2 KB

    const int tid  = threadIdx.x;
    if (tid == 0) lcnt = 0;
    const int il   = tid & (IPB - 1);
    const int seg  = tid / IPB;           // 0..31
    const int gi   = blockIdx.x * IPB + il;
    const int base = seg * 128;

    // ---- stage pos+ori into LDS ----
    for (int k = 0; k < NPART / NTHR; ++k) {
        const int j = k * NTHR + tid;
        const float2 pj = pos[j];
        const float2 uj = ori[j];
        pu[j] = make_float4(pj.x, pj.y, uj.x, uj.y);
    }
    __syncthreads();

    // ---- pairwise phase ----
    const float pix = pu[gi].x, piy = pu[gi].y;
    float nr = 0.f, sx = 0.f, sy = 0.f, oxs = 0.f, oys = 0.f;
    #pragma unroll 4
    for (int t = 0; t < 128; ++t) {
        const int j = base + ((t + seg) & 127);   // stagger: conflict-free
        const float4 v = pu[j];
        const float dx = v.x - pix, dy = v.y - piy;
        const float r2 = fmaf(dx, dx, dy * dy);
        const bool oc = (r2 <= RORC2);            // inside_Ro (diag included)
        oxs += oc ? v.z : 0.f;
        oys += oc ? v.w : 0.f;
        if (r2 <= RCAND2 && r2 > 0.f) {           // rare (~0.16% of pairs)
            if (r2 <= RR2) {
                // in_front fails <=> dot<=0 && cross>=0
                const float dt_ = fmaf(dx, v.z, dy * v.w);
                const float cr_ = fmaf(dy, v.z, -dx * v.w);
                const bool fail = (dt_ <= 0.f) && (cr_ >= 0.f);
                if (!fail) { nr += 1.f; sx += v.x; sy += v.y; }
            }
            const int slot = atomicAdd(&lcnt, 1); // collision candidate
            if (slot < CAP) lpairs[slot] = (il << 12) | j;
        }
    }
    __syncthreads();                       // lcnt final; pu reads done
    sred[0 * NTHR + tid] = nr;
    sred[1 * NTHR + tid] = sx;
    sred[2 * NTHR + tid] = sy;
    sred[3 * NTHR + tid] = oxs;
    sred[4 * NTHR + tid] = oys;
    __syncthreads();
    if (tid < 5 * IPB) {                   // same order as R1 -> bit-identical
        const int q = tid / IPB, ii = tid & (IPB - 1);
        float acc = 0.f;
        #pragma unroll
        for (int s = 0; s < 32; ++s) acc += sred[q * NTHR + ii + IPB * s];
        res[q][ii] = acc;
    }
    // ---- flush candidate list (independent of sred/res) ----
    const int n_l = (lcnt < CAP) ? lcnt : CAP;
    for (int e = tid; e < n_l; e += NTHR)
        pairs_g[blockIdx.x * CAP + e] = lpairs[e];
    if (tid == 0) counts[blockIdx.x] = n_l;
    __syncthreads();

    // ---- mean of all positions (n_a == N) — same order as R1 epilogue ----
    float mx = 0.f, my = 0.f;
    for (int k = 0; k < NPART / NTHR; ++k) {
        const float4 v = pu[k * NTHR + tid];
        mx += v.x; my += v.y;
    }
    sred[tid] = mx; sred[NTHR + tid] = my;
    __syncthreads();
    for (int s = NTHR / 2; s > 0; s >>= 1) {
        if (tid < s) { sred[tid] += sred[tid + s]; sred[NTHR + tid] += sred[NTHR + tid + s]; }
        __syncthreads();
    }
    const float cmx = sred[0]    * (1.f / NPART);
    const float cmy = sred[NTHR] * (1.f / NPART);

    // ---- per-i epilogue (8 threads) ----
    if (tid < IPB) {
        const int g2 = blockIdx.x * IPB + tid;
        const float2 p = make_float2(pu[g2].x, pu[g2].y);
        const float2 u = make_float2(pu[g2].z, pu[g2].w);
        const float nrv = res[0][tid], sxv = res[1][tid], syv = res[2][tid];
        const float osx = res[3][tid], osy = res[4][tid];

        const float inv = 1.f / fmaxf(nrv, 1.f);
        const float sg  = (nrv > 0.f) ? 1.f : 0.f;
        const float Sx = sxv * inv - p.x * sg;
        const float Sy = syv * inv - p.y * sg;
        const float dxv = -Sx, dyv = -Sy;        // d = -S

        const float Psx = cmx - p.x;
        const float Psy = cmy - p.y;

        float sd, cd;
        sincosf(Deltas[0], &sd, &cd);
        const float Lx = Psx * cd - Psy * sd;    // Ps * exp(+i*Delta)
        const float Ly = Psx * sd + Psy * cd;
        const float Rx = Psx * cd + Psy * sd;    // Ps * exp(-i*Delta)
        const float Ry = Psy * cd - Psx * sd;

        const float no  = fmaxf(sqrtf(osx * osx + osy * osy + 1e-30f), EPSF);
        const float nl  = fmaxf(sqrtf(Lx * Lx + Ly * Ly + 1e-30f), EPSF);
        const float nrr = fmaxf(sqrtf(Rx * Rx + Ry * Ry + 1e-30f), EPSF);
        const float csl = (Lx * osx + Ly * osy) / (nl * no);
        const float csr = (Rx * osx + Ry * osy) / (nrr * no);
        const bool left = (csl >= csr);
        const float bx = left ? Lx : Rx;
        const float by = left ? Ly : Ry;

        float cx, cy;
        if (dxv != 0.f || dyv != 0.f)    { cx = dxv; cy = dyv; }
        else if (bx != 0.f || by != 0.f) { cx = bx;  cy = by;  }
        else                             { cx = 1.f; cy = 0.f; }

        const float dt_ = cx * u.x + cy * u.y;
        const float cr_ = cy * u.x - cx * u.y;
        const float sin_t = cr_ / sqrtf(dt_ * dt_ + cr_ * cr_);

        const float ang = C_ROT * sin_t + (rot_noise[g2] * C_RN1) * C_SQDT;
        float sa, ca;
        sincosf(ang, &sa, &ca);
        const float nux = u.x * ca - u.y * sa;
        const float nuy = u.x * sa + u.y * ca;

        const float2 tn = trans_noise[g2];
        const float tvx = C_TRV * u.x + ((tn.x * C_HALF) * C_SQ2T) * C_SQDT;
        const float tvy = C_TRV * u.y + ((tn.y * C_HALF) * C_SQ2T) * C_SQDT;

        out[1 * NPART + g2] = make_float2(nux, nuy);
        out[2 * NPART + g2] = make_float2(osx, osy);
        out[3 * NPART + g2] = make_float2(Lx, Ly);
        out[4 * NPART + g2] = make_float2(Rx, Ry);
        pA[g2] = make_float2(p.x + tvx, p.y + tvy);
    }
}

// ---------------------------------------------------------------------------
// Kernel 2: all 3 collision passes over sparse candidate lists, one block.
// Thread b owns list b (pairs (i,j) with i in [8b, 8b+8)); only the owner
// writes macc[i], so no atomics. __syncthreads separates read/write phases.
// ---------------------------------------------------------------------------
__global__ __launch_bounds__(NBLK) void collide_sparse(
        const float2* __restrict__ pA, const int* __restrict__ counts,
        const int* __restrict__ pairs_g, float2* __restrict__ out0) {
    __shared__ float2 ppos[NPART];        // 32 KB
    __shared__ float2 macc[NPART];        // 32 KB

    const int tid = threadIdx.x;          // 512 threads == NBLK lists
    for (int k = 0; k < NPART / NBLK; ++k) {
        const int i = k * NBLK + tid;
        ppos[i] = pA[i];
    }
    const int cnt = counts[tid];
    __syncthreads();

    for (int pass = 0; pass < 3; ++pass) {
        for (int k = 0; k < NPART / NBLK; ++k)
            macc[k * NBLK + tid] = make_float2(0.f, 0.f);
        __syncthreads();
        for (int e = 0; e < cnt; ++e) {
            const int pk = pairs_g[tid * CAP + e];
            const int i  = tid * IPB + (pk >> 12);
            const int j  = pk & (NPART - 1);
            const float2 pi = ppos[i];
            const float2 pj = ppos[j];
            const float dx = pj.x - pi.x, dy = pj.y - pi.y;
            const float r2 = fmaf(dx, dx, dy * dy);
            if (r2 <= TWORC2 && r2 > 0.f) {
                const float ab = sqrtf(r2);
                const float s = (C21RC - ab) * 0.5f / ab;
                macc[i].x += dx * s;      // single writer: thread tid owns i
                macc[i].y += dy * s;
            }
        }
        __syncthreads();
        for (int k = 0; k < NPART / NBLK; ++k) {
            const int i = k * NBLK + tid;
            ppos[i].x -= macc[i].x;
            ppos[i].y -= macc[i].y;
        }
        __syncthreads();
    }
    for (int k = 0; k < NPART / NBLK; ++k) {
        const int i = k * NBLK + tid;
        out0[i] = ppos[i];
    }
}

extern "C" void kernel_launch(void* const* d_in, const int* in_sizes, int n_in,
                              void* d_out, int out_size, void* d_ws, size_t ws_size,
                              hipStream_t stream) {
    const float2* pos = (const float2*)d_in[0];
    const float2* ori = (const float2*)d_in[1];
    const float*  del = (const float*)d_in[2];
    const float*  rn  = (const float*)d_in[3];
    const float2* tn  = (const float2*)d_in[4];

    float2* pA     = (float2*)d_ws;                               // 32 KB
    int*    counts = (int*)((char*)d_ws + NPART * sizeof(float2));// 2 KB
    int*    pairs  = counts + NBLK;                               // 1 MB
    float2* o2     = (float2*)d_out;                              // [5][N] float2

    fused_main<<<dim3(NBLK), dim3(NTHR), 0, stream>>>(pos, ori, del, rn, tn,
                                                      o2, pA, counts, pairs);
    collide_sparse<<<dim3(1), dim3(NBLK), 0, stream>>>(pA, counts, pairs, o2);
}

// Round 4
// 141.709 us; speedup vs baseline: 2.0115x; 1.0064x over previous
//
#include <hip/hip_runtime.h>
#include <math.h>

#define NPART 4096
#define NBLK  512
#define NTHR  256
#define IPB   8     // particles (i) per block in kernel 1
#define PCAP  64    // max candidates per particle (expected ~7, center ~13)

// Constants, rounded exactly as the reference's weak-typed doubles -> f32
constexpr float RORC   = (float)(2.5e-5 + 3.15e-6);    // RO + RC
constexpr float RORC2  = RORC * RORC;
constexpr float RRF    = 8e-6f;                        // RR
constexpr float RR2    = RRF * RRF;
constexpr float TWORC  = (float)(2.0 * 3.15e-6);       // 2*RC
constexpr float TWORC2 = TWORC * TWORC;
constexpr float C21RC  = (float)(2.1 * 3.15e-6);       // 2.1*RC
constexpr float RCAND2 = 1.6e-9f;                      // (4e-5)^2 candidate radius^2
constexpr float C_ROT  = (float)(0.2 * 25.0 * 0.0028); // dt*Gamma*DR
constexpr float C_RN1  = (float)0.07483314773547883;   // f32(sqrt(2*DR))
constexpr float C_SQDT = (float)0.4472135954999579;    // f32(sqrt(dt))
constexpr float C_TRV  = (float)(0.2 * 5e-7);          // dt*velocity
constexpr float C_HALF = (float)0.7071067811865476;    // f32(sqrt(0.5))
constexpr float C_SQ2T = (float)1.6733200530681511e-07;// f32(sqrt(2*DT_TRANS))
constexpr float EPSF   = 1e-14f;

// ---------------------------------------------------------------------------
// Kernel 1: pair sums + per-block mean + epilogue + per-PARTICLE collision
// candidate lists. 512 blocks x 256 thr; block owns 8 i's, 32 j-segs of 128.
// Reduction orders identical to R1 (bit-exact sections 1..4).
// ---------------------------------------------------------------------------
__global__ __launch_bounds__(NTHR) void fused_main(
        const float2* __restrict__ pos, const float2* __restrict__ ori,
        const float* __restrict__ Deltas, const float* __restrict__ rot_noise,
        const float2* __restrict__ trans_noise,
        float2* __restrict__ out, float2* __restrict__ pA,
        int* __restrict__ counts_g, int* __restrict__ pairs_g) {
    __shared__ float4 pu[NPART];          // 64 KB
    __shared__ float  sred[5 * NTHR];     // 5 KB
    __shared__ float  res[5][IPB];
    __shared__ int    lcnt8[IPB];
    __shared__ int    lpairs[IPB][PCAP];  // 2 KB

    const int tid  = threadIdx.x;
    if (tid < IPB) lcnt8[tid] = 0;
    const int il   = tid & (IPB - 1);
    const int seg  = tid / IPB;           // 0..31
    const int gi   = blockIdx.x * IPB + il;
    const int base = seg * 128;

    // ---- stage pos+ori into LDS ----
    for (int k = 0; k < NPART / NTHR; ++k) {
        const int j = k * NTHR + tid;
        const float2 pj = pos[j];
        const float2 uj = ori[j];
        pu[j] = make_float4(pj.x, pj.y, uj.x, uj.y);
    }
    __syncthreads();

    // ---- pairwise phase ----
    const float pix = pu[gi].x, piy = pu[gi].y;
    float nr = 0.f, sx = 0.f, sy = 0.f, oxs = 0.f, oys = 0.f;
    #pragma unroll 4
    for (int t = 0; t < 128; ++t) {
        const int j = base + ((t + seg) & 127);   // stagger: conflict-free
        const float4 v = pu[j];
        const float dx = v.x - pix, dy = v.y - piy;
        const float r2 = fmaf(dx, dx, dy * dy);
        const bool oc = (r2 <= RORC2);            // inside_Ro (diag included)
        oxs += oc ? v.z : 0.f;
        oys += oc ? v.w : 0.f;
        if (r2 <= RCAND2 && r2 > 0.f) {           // rare (~0.16% of pairs)
            if (r2 <= RR2) {
                // in_front fails <=> dot<=0 && cross>=0
                const float dt_ = fmaf(dx, v.z, dy * v.w);
                const float cr_ = fmaf(dy, v.z, -dx * v.w);
                const bool fail = (dt_ <= 0.f) && (cr_ >= 0.f);
                if (!fail) { nr += 1.f; sx += v.x; sy += v.y; }
            }
            const int slot = atomicAdd(&lcnt8[il], 1);
            if (slot < PCAP) lpairs[il][slot] = j;
        }
    }
    __syncthreads();                       // lcnt8 final; pu reads done
    sred[0 * NTHR + tid] = nr;
    sred[1 * NTHR + tid] = sx;
    sred[2 * NTHR + tid] = sy;
    sred[3 * NTHR + tid] = oxs;
    sred[4 * NTHR + tid] = oys;
    __syncthreads();
    if (tid < 5 * IPB) {                   // same order as R1 -> bit-identical
        const int q = tid / IPB, ii = tid & (IPB - 1);
        float acc = 0.f;
        #pragma unroll
        for (int s = 0; s < 32; ++s) acc += sred[q * NTHR + ii + IPB * s];
        res[q][ii] = acc;
    }
    // ---- flush per-particle candidate lists ----
    if (tid < IPB)
        counts_g[blockIdx.x * IPB + tid] = min(lcnt8[tid], PCAP);
    for (int idx = tid; idx < IPB * PCAP; idx += NTHR) {
        const int il2 = idx / PCAP, e = idx & (PCAP - 1);
        if (e < min(lcnt8[il2], PCAP))
            pairs_g[blockIdx.x * (IPB * PCAP) + idx] = lpairs[il2][e];
    }
    __syncthreads();

    // ---- mean of all positions (n_a == N) — same order as R1 epilogue ----
    float mx = 0.f, my = 0.f;
    for (int k = 0; k < NPART / NTHR; ++k) {
        const float4 v = pu[k * NTHR + tid];
        mx += v.x; my += v.y;
    }
    sred[tid] = mx; sred[NTHR + tid] = my;
    __syncthreads();
    for (int s = NTHR / 2; s > 0; s >>= 1) {
        if (tid < s) { sred[tid] += sred[tid + s]; sred[NTHR + tid] += sred[NTHR + tid + s]; }
        __syncthreads();
    }
    const float cmx = sred[0]    * (1.f / NPART);
    const float cmy = sred[NTHR] * (1.f / NPART);

    // ---- per-i epilogue (8 threads) ----
    if (tid < IPB) {
        const int g2 = blockIdx.x * IPB + tid;
        const float2 p = make_float2(pu[g2].x, pu[g2].y);
        const float2 u = make_float2(pu[g2].z, pu[g2].w);
        const float nrv = res[0][tid], sxv = res[1][tid], syv = res[2][tid];
        const float osx = res[3][tid], osy = res[4][tid];

        const float inv = 1.f / fmaxf(nrv, 1.f);
        const float sg  = (nrv > 0.f) ? 1.f : 0.f;
        const float Sx = sxv * inv - p.x * sg;
        const float Sy = syv * inv - p.y * sg;
        const float dxv = -Sx, dyv = -Sy;        // d = -S

        const float Psx = cmx - p.x;
        const float Psy = cmy - p.y;

        float sd, cd;
        sincosf(Deltas[0], &sd, &cd);
        const float Lx = Psx * cd - Psy * sd;    // Ps * exp(+i*Delta)
        const float Ly = Psx * sd + Psy * cd;
        const float Rx = Psx * cd + Psy * sd;    // Ps * exp(-i*Delta)
        const float Ry = Psy * cd - Psx * sd;

        const float no  = fmaxf(sqrtf(osx * osx + osy * osy + 1e-30f), EPSF);
        const float nl  = fmaxf(sqrtf(Lx * Lx + Ly * Ly + 1e-30f), EPSF);
        const float nrr = fmaxf(sqrtf(Rx * Rx + Ry * Ry + 1e-30f), EPSF);
        const float csl = (Lx * osx + Ly * osy) / (nl * no);
        const float csr = (Rx * osx + Ry * osy) / (nrr * no);
        const bool left = (csl >= csr);
        const float bx = left ? Lx : Rx;
        const float by = left ? Ly : Ry;

        float cx, cy;
        if (dxv != 0.f || dyv != 0.f)    { cx = dxv; cy = dyv; }
        else if (bx != 0.f || by != 0.f) { cx = bx;  cy = by;  }
        else                             { cx = 1.f; cy = 0.f; }

        const float dt_ = cx * u.x + cy * u.y;
        const float cr_ = cy * u.x - cx * u.y;
        const float sin_t = cr_ / sqrtf(dt_ * dt_ + cr_ * cr_);

        const float ang = C_ROT * sin_t + (rot_noise[g2] * C_RN1) * C_SQDT;
        float sa, ca;
        sincosf(ang, &sa, &ca);
        const float nux = u.x * ca - u.y * sa;
        const float nuy = u.x * sa + u.y * ca;

        const float2 tn = trans_noise[g2];
        const float tvx = C_TRV * u.x + ((tn.x * C_HALF) * C_SQ2T) * C_SQDT;
        const float tvy = C_TRV * u.y + ((tn.y * C_HALF) * C_SQ2T) * C_SQDT;

        out[1 * NPART + g2] = make_float2(nux, nuy);
        out[2 * NPART + g2] = make_float2(osx, osy);
        out[3 * NPART + g2] = make_float2(Lx, Ly);
        out[4 * NPART + g2] = make_float2(Rx, Ry);
        pA[g2] = make_float2(p.x + tvx, p.y + tvy);
    }
}

// ---------------------------------------------------------------------------
// Kernel 2: 3 collision passes. One block x 1024 thr; thread owns particles
// 4t..4t+3, each with its own candidate list -> pure REGISTER accumulation
// (no LDS RMW chain). Positions cached in registers across passes.
// ---------------------------------------------------------------------------
__global__ __launch_bounds__(1024) void collide_sparse(
        const float2* __restrict__ pA, const int* __restrict__ counts_g,
        const int* __restrict__ pairs_g, float2* __restrict__ out0) {
    __shared__ float2 ppos[NPART];        // 32 KB

    const int tid = threadIdx.x;
    for (int k = 0; k < NPART / 1024; ++k)
        ppos[k * 1024 + tid] = pA[k * 1024 + tid];

    int   c[4], base[4];
    float pix[4], piy[4];
    #pragma unroll
    for (int q = 0; q < 4; ++q) {
        const int p = tid * 4 + q;
        c[q]    = counts_g[p];
        base[q] = (p >> 3) * (IPB * PCAP) + (p & (IPB - 1)) * PCAP;
    }
    __syncthreads();
    #pragma unroll
    for (int q = 0; q < 4; ++q) {
        const float2 v = ppos[tid * 4 + q];
        pix[q] = v.x; piy[q] = v.y;
    }

    for (int pass = 0; pass < 3; ++pass) {
        float mvx[4], mvy[4];
        #pragma unroll
        for (int q = 0; q < 4; ++q) {
            float ax = 0.f, ay = 0.f;
            for (int e = 0; e < c[q]; ++e) {
                const int j = pairs_g[base[q] + e];
                const float2 pj = ppos[j];
                const float dx = pj.x - pix[q], dy = pj.y - piy[q];
                const float r2 = fmaf(dx, dx, dy * dy);
                if (r2 <= TWORC2 && r2 > 0.f) {
                    const float ab = sqrtf(r2);
                    const float s = (C21RC - ab) * 0.5f / ab;
                    ax = fmaf(dx, s, ax);
                    ay = fmaf(dy, s, ay);
                }
            }
            mvx[q] = ax; mvy[q] = ay;
        }
        __syncthreads();                  // all reads of ppos done
        #pragma unroll
        for (int q = 0; q < 4; ++q) {
            pix[q] -= mvx[q]; piy[q] -= mvy[q];
            ppos[tid * 4 + q] = make_float2(pix[q], piy[q]);
        }
        __syncthreads();                  // writes visible before next pass
    }
    for (int k = 0; k < NPART / 1024; ++k)
        out0[k * 1024 + tid] = ppos[k * 1024 + tid];
}

extern "C" void kernel_launch(void* const* d_in, const int* in_sizes, int n_in,
                              void* d_out, int out_size, void* d_ws, size_t ws_size,
                              hipStream_t stream) {
    const float2* pos = (const float2*)d_in[0];
    const float2* ori = (const float2*)d_in[1];
    const float*  del = (const float*)d_in[2];
    const float*  rn  = (const float*)d_in[3];
    const float2* tn  = (const float2*)d_in[4];

    float2* pA     = (float2*)d_ws;                                // 32 KB
    int*    counts = (int*)((char*)d_ws + NPART * sizeof(float2)); // 16 KB
    int*    pairs  = counts + NPART;                               // 1 MB
    float2* o2     = (float2*)d_out;                               // [5][N] float2

    fused_main<<<dim3(NBLK), dim3(NTHR), 0, stream>>>(pos, ori, del, rn, tn,
                                                      o2, pA, counts, pairs);
    collide_sparse<<<dim3(1), dim3(1024), 0, stream>>>(pA, counts, pairs, o2);
}

// Round 6
// 110.314 us; speedup vs baseline: 2.5839x; 1.2846x over previous
//
#include <hip/hip_runtime.h>
#include <math.h>

#define NPART 4096
#define NBLK  512
#define NTHR  256
#define IPB   8     // particles (i) per block in kernel 1
#define CAP   512   // max candidate pairs per block (expected ~52)
#define MAXP  (NBLK * CAP)   // flat pair array capacity (worst case exact)

// Constants, rounded exactly as the reference's weak-typed doubles -> f32
constexpr float RORC   = (float)(2.5e-5 + 3.15e-6);    // RO + RC
constexpr float RORC2  = RORC * RORC;
constexpr float RRF    = 8e-6f;                        // RR
constexpr float RR2    = RRF * RRF;
constexpr float TWORC  = (float)(2.0 * 3.15e-6);       // 2*RC
constexpr float TWORC2 = TWORC * TWORC;
constexpr float C21RC  = (float)(2.1 * 3.15e-6);       // 2.1*RC
constexpr float RCAND2 = 1.6e-9f;                      // (4e-5)^2 candidate radius^2
constexpr float C_ROT  = (float)(0.2 * 25.0 * 0.0028); // dt*Gamma*DR
constexpr float C_RN1  = (float)0.07483314773547883;   // f32(sqrt(2*DR))
constexpr float C_SQDT = (float)0.4472135954999579;    // f32(sqrt(dt))
constexpr float C_TRV  = (float)(0.2 * 5e-7);          // dt*velocity
constexpr float C_HALF = (float)0.7071067811865476;    // f32(sqrt(0.5))
constexpr float C_SQ2T = (float)1.6733200530681511e-07;// f32(sqrt(2*DT_TRANS))
constexpr float EPSF   = 1e-14f;

// ---------------------------------------------------------------------------
// Kernel 0: zero the flat-pair counter (graph-capture-safe replacement for
// hipMemsetAsync, which coincided with an infra failure in R5).
// ---------------------------------------------------------------------------
__global__ void zero_counter(int* __restrict__ counter) {
    *counter = 0;
}

// ---------------------------------------------------------------------------
// Kernel 1: pair sums + per-block mean + epilogue + flat collision-candidate
// compaction. 512 blocks x 256 thr; block owns 8 i's, 32 j-segs of 128.
// Reduction orders identical to R1 (bit-exact sections 1..4).
// ---------------------------------------------------------------------------
__global__ __launch_bounds__(NTHR) void fused_main(
        const float2* __restrict__ pos, const float2* __restrict__ ori,
        const float* __restrict__ Deltas, const float* __restrict__ rot_noise,
        const float2* __restrict__ trans_noise,
        float2* __restrict__ out, float2* __restrict__ pA,
        int* __restrict__ counter, int* __restrict__ pairs_g) {
    __shared__ float4 pu[NPART];          // 64 KB
    __shared__ float  sred[5 * NTHR];     // 5 KB
    __shared__ float  res[5][IPB];
    __shared__ int    lcnt, lbase;
    __shared__ int    lpairs[CAP];        // 2 KB

    const int tid  = threadIdx.x;
    if (tid == 0) lcnt = 0;
    const int il   = tid & (IPB - 1);
    const int seg  = tid / IPB;           // 0..31
    const int gi   = blockIdx.x * IPB + il;
    const int base = seg * 128;

    // ---- stage pos+ori into LDS ----
    for (int k = 0; k < NPART / NTHR; ++k) {
        const int j = k * NTHR + tid;
        const float2 pj = pos[j];
        const float2 uj = ori[j];
        pu[j] = make_float4(pj.x, pj.y, uj.x, uj.y);
    }
    __syncthreads();

    // ---- pairwise phase ----
    const float pix = pu[gi].x, piy = pu[gi].y;
    float nr = 0.f, sx = 0.f, sy = 0.f, oxs = 0.f, oys = 0.f;
    #pragma unroll 4
    for (int t = 0; t < 128; ++t) {
        const int j = base + ((t + seg) & 127);   // stagger: conflict-free
        const float4 v = pu[j];
        const float dx = v.x - pix, dy = v.y - piy;
        const float r2 = fmaf(dx, dx, dy * dy);
        const bool oc = (r2 <= RORC2);            // inside_Ro (diag included)
        oxs += oc ? v.z : 0.f;
        oys += oc ? v.w : 0.f;
        if (r2 <= RCAND2 && r2 > 0.f) {           // rare (~0.16% of pairs)
            if (r2 <= RR2) {
                // in_front fails <=> dot<=0 && cross>=0
                const float dt_ = fmaf(dx, v.z, dy * v.w);
                const float cr_ = fmaf(dy, v.z, -dx * v.w);
                const bool fail = (dt_ <= 0.f) && (cr_ >= 0.f);
                if (!fail) { nr += 1.f; sx += v.x; sy += v.y; }
            }
            const int slot = atomicAdd(&lcnt, 1); // candidate (i global, j)
            if (slot < CAP) lpairs[slot] = (gi << 12) | j;
        }
    }
    __syncthreads();                       // lcnt final; pu reads done
    sred[0 * NTHR + tid] = nr;
    sred[1 * NTHR + tid] = sx;
    sred[2 * NTHR + tid] = sy;
    sred[3 * NTHR + tid] = oxs;
    sred[4 * NTHR + tid] = oys;
    if (tid == 0) {
        const int n_l = (lcnt < CAP) ? lcnt : CAP;
        lbase = atomicAdd(counter, n_l);   // device-scope, reserve flat slots
        lcnt  = n_l;
    }
    __syncthreads();
    if (tid < 5 * IPB) {                   // same order as R1 -> bit-identical
        const int q = tid / IPB, ii = tid & (IPB - 1);
        float acc = 0.f;
        #pragma unroll
        for (int s = 0; s < 32; ++s) acc += sred[q * NTHR + ii + IPB * s];
        res[q][ii] = acc;
    }
    // ---- flush candidate list to flat global array ----
    for (int e = tid; e < lcnt; e += NTHR)
        pairs_g[lbase + e] = lpairs[e];
    __syncthreads();

    // ---- mean of all positions (n_a == N) — same order as R1 epilogue ----
    float mx = 0.f, my = 0.f;
    for (int k = 0; k < NPART / NTHR; ++k) {
        const float4 v = pu[k * NTHR + tid];
        mx += v.x; my += v.y;
    }
    sred[tid] = mx; sred[NTHR + tid] = my;
    __syncthreads();
    for (int s = NTHR / 2; s > 0; s >>= 1) {
        if (tid < s) { sred[tid] += sred[tid + s]; sred[NTHR + tid] += sred[NTHR + tid + s]; }
        __syncthreads();
    }
    const float cmx = sred[0]    * (1.f / NPART);
    const float cmy = sred[NTHR] * (1.f / NPART);

    // ---- per-i epilogue (8 threads) ----
    if (tid < IPB) {
        const int g2 = blockIdx.x * IPB + tid;
        const float2 p = make_float2(pu[g2].x, pu[g2].y);
        const float2 u = make_float2(pu[g2].z, pu[g2].w);
        const float nrv = res[0][tid], sxv = res[1][tid], syv = res[2][tid];
        const float osx = res[3][tid], osy = res[4][tid];

        const float inv = 1.f / fmaxf(nrv, 1.f);
        const float sg  = (nrv > 0.f) ? 1.f : 0.f;
        const float Sx = sxv * inv - p.x * sg;
        const float Sy = syv * inv - p.y * sg;
        const float dxv = -Sx, dyv = -Sy;        // d = -S

        const float Psx = cmx - p.x;
        const float Psy = cmy - p.y;

        float sd, cd;
        sincosf(Deltas[0], &sd, &cd);
        const float Lx = Psx * cd - Psy * sd;    // Ps * exp(+i*Delta)
        const float Ly = Psx * sd + Psy * cd;
        const float Rx = Psx * cd + Psy * sd;    // Ps * exp(-i*Delta)
        const float Ry = Psy * cd - Psx * sd;

        const float no  = fmaxf(sqrtf(osx * osx + osy * osy + 1e-30f), EPSF);
        const float nl  = fmaxf(sqrtf(Lx * Lx + Ly * Ly + 1e-30f), EPSF);
        const float nrr = fmaxf(sqrtf(Rx * Rx + Ry * Ry + 1e-30f), EPSF);
        const float csl = (Lx * osx + Ly * osy) / (nl * no);
        const float csr = (Rx * osx + Ry * osy) / (nrr * no);
        const bool left = (csl >= csr);
        const float bx = left ? Lx : Rx;
        const float by = left ? Ly : Ry;

        float cx, cy;
        if (dxv != 0.f || dyv != 0.f)    { cx = dxv; cy = dyv; }
        else if (bx != 0.f || by != 0.f) { cx = bx;  cy = by;  }
        else                             { cx = 1.f; cy = 0.f; }

        const float dt_ = cx * u.x + cy * u.y;
        const float cr_ = cy * u.x - cx * u.y;
        const float sin_t = cr_ / sqrtf(dt_ * dt_ + cr_ * cr_);

        const float ang = C_ROT * sin_t + (rot_noise[g2] * C_RN1) * C_SQDT;
        float sa, ca;
        sincosf(ang, &sa, &ca);
        const float nux = u.x * ca - u.y * sa;
        const float nuy = u.x * sa + u.y * ca;

        const float2 tn = trans_noise[g2];
        const float tvx = C_TRV * u.x + ((tn.x * C_HALF) * C_SQ2T) * C_SQDT;
        const float tvy = C_TRV * u.y + ((tn.y * C_HALF) * C_SQ2T) * C_SQDT;

        out[1 * NPART + g2] = make_float2(nux, nuy);
        out[2 * NPART + g2] = make_float2(osx, osy);
        out[3 * NPART + g2] = make_float2(Lx, Ly);
        out[4 * NPART + g2] = make_float2(Rx, Ry);
        pA[g2] = make_float2(p.x + tvx, p.y + tvy);
    }
}

// ---------------------------------------------------------------------------
// Kernel 2: 3 collision passes. One block x 1024 thr grid-striding the FLAT
// pair list: coalesced independent loads, LDS float atomicAdd accumulation
// (each ordered pair (i,j) accumulates into i; (j,i) is also in the list).
// ---------------------------------------------------------------------------
__global__ __launch_bounds__(1024) void collide_sparse(
        const float2* __restrict__ pA, const int* __restrict__ counter,
        const int* __restrict__ pairs_g, float2* __restrict__ out0) {
    __shared__ float2 ppos[NPART];        // 32 KB
    __shared__ float  macx[NPART];        // 16 KB
    __shared__ float  macy[NPART];        // 16 KB

    const int tid = threadIdx.x;
    for (int k = 0; k < NPART / 1024; ++k)
        ppos[k * 1024 + tid] = pA[k * 1024 + tid];
    int nc = *counter;
    nc = (nc < MAXP) ? nc : MAXP;
    __syncthreads();

    for (int pass = 0; pass < 3; ++pass) {
        for (int k = 0; k < NPART / 1024; ++k) {
            macx[k * 1024 + tid] = 0.f;
            macy[k * 1024 + tid] = 0.f;
        }
        __syncthreads();
        for (int e = tid; e < nc; e += 1024) {     // coalesced, independent
            const int pk = pairs_g[e];
            const int i  = pk >> 12;
            const int j  = pk & (NPART - 1);
            const float2 pi = ppos[i];
            const float2 pj = ppos[j];
            const float dx = pj.x - pi.x, dy = pj.y - pi.y;
            const float r2 = fmaf(dx, dx, dy * dy);
            if (r2 <= TWORC2 && r2 > 0.f) {
                const float ab = sqrtf(r2);
                const float s = (C21RC - ab) * 0.5f / ab;
                atomicAdd(&macx[i], dx * s);       // ds_add_f32
                atomicAdd(&macy[i], dy * s);
            }
        }
        __syncthreads();
        for (int k = 0; k < NPART / 1024; ++k) {
            const int i = k * 1024 + tid;
            ppos[i].x -= macx[i];
            ppos[i].y -= macy[i];
        }
        __syncthreads();
    }
    for (int k = 0; k < NPART / 1024; ++k)
        out0[k * 1024 + tid] = ppos[k * 1024 + tid];
}

extern "C" void kernel_launch(void* const* d_in, const int* in_sizes, int n_in,
                              void* d_out, int out_size, void* d_ws, size_t ws_size,
                              hipStream_t stream) {
    const float2* pos = (const float2*)d_in[0];
    const float2* ori = (const float2*)d_in[1];
    const float*  del = (const float*)d_in[2];
    const float*  rn  = (const float*)d_in[3];
    const float2* tn  = (const float2*)d_in[4];

    float2* pA      = (float2*)d_ws;                                // 32 KB
    int*    counter = (int*)((char*)d_ws + NPART * sizeof(float2)); // 4 B (+pad)
    int*    pairs   = counter + 16;                                 // 1 MB
    float2* o2      = (float2*)d_out;                               // [5][N] float2

    zero_counter<<<dim3(1), dim3(1), 0, stream>>>(counter);
    fused_main<<<dim3(NBLK), dim3(NTHR), 0, stream>>>(pos, ori, del, rn, tn,
                                                      o2, pA, counter, pairs);
    collide_sparse<<<dim3(1), dim3(1024), 0, stream>>>(pA, counter, pairs, o2);
}

// Round 7
// 103.105 us; speedup vs baseline: 2.7646x; 1.0699x over previous
//
#include <hip/hip_runtime.h>
#include <math.h>

#define NPART 4096
#define NBLK  512
#define NTHR  256
#define IPB   8     // particles (i) per block in kernel 1
#define CAP   512   // max candidate pairs per block (expected ~52, center ~104)
#define MAXP  (NBLK * CAP)
#define KREG  32    // register-preloaded pairs per thread in collide (32*1024=32768 >= ~27K)

// Constants, rounded exactly as the reference's weak-typed doubles -> f32
constexpr float RORC   = (float)(2.5e-5 + 3.15e-6);    // RO + RC
constexpr float RORC2  = RORC * RORC;
constexpr float RRF    = 8e-6f;                        // RR
constexpr float RR2    = RRF * RRF;
constexpr float TWORC  = (float)(2.0 * 3.15e-6);       // 2*RC
constexpr float TWORC2 = TWORC * TWORC;
constexpr float C21RC  = (float)(2.1 * 3.15e-6);       // 2.1*RC
constexpr float RCAND2 = 1.6e-9f;                      // (4e-5)^2 > RORC^2: Ro-test nests inside
constexpr float C_ROT  = (float)(0.2 * 25.0 * 0.0028); // dt*Gamma*DR
constexpr float C_RN1  = (float)0.07483314773547883;   // f32(sqrt(2*DR))
constexpr float C_SQDT = (float)0.4472135954999579;    // f32(sqrt(dt))
constexpr float C_TRV  = (float)(0.2 * 5e-7);          // dt*velocity
constexpr float C_HALF = (float)0.7071067811865476;    // f32(sqrt(0.5))
constexpr float C_SQ2T = (float)1.6733200530681511e-07;// f32(sqrt(2*DT_TRANS))
constexpr float EPSF   = 1e-14f;

// ---------------------------------------------------------------------------
// Kernel 0: zero the flat-pair counter (graph-capture-safe).
// ---------------------------------------------------------------------------
__global__ void zero_counter(int* __restrict__ counter) {
    *counter = 0;
}

// ---------------------------------------------------------------------------
// Kernel 1: pair sums + per-block mean + epilogue + flat collision-candidate
// compaction. 512 blocks x 256 thr; block owns 8 i's, 32 j-segs of 128.
// Hot loop touches ONLY positions (2 j's per ds_read_b128, broadcast,
// conflict-free); ALL conditional work (Ro-sum, in_front, pair append) lives
// in the rare r2<=RCAND2 branch (~0.16% of pairs + diagonal).
// ---------------------------------------------------------------------------
__global__ __launch_bounds__(NTHR) void fused_main(
        const float2* __restrict__ pos, const float2* __restrict__ ori,
        const float* __restrict__ Deltas, const float* __restrict__ rot_noise,
        const float2* __restrict__ trans_noise,
        float2* __restrict__ out, float2* __restrict__ pA,
        int* __restrict__ counter, int* __restrict__ pairs_g) {
    __shared__ float4 pp4[NPART / 2];     // 32 KB, positions as float2[NPART]
    __shared__ float2 pori_s[NPART];      // 32 KB, orientations
    __shared__ float  sred[5 * NTHR];     // 5 KB
    __shared__ float  res[5][IPB];
    __shared__ int    lcnt, lbase;
    __shared__ int    lpairs[CAP];        // 2 KB
    float2* ppos_s = (float2*)pp4;

    const int tid  = threadIdx.x;
    if (tid == 0) lcnt = 0;
    const int il   = tid & (IPB - 1);
    const int seg  = tid / IPB;           // 0..31
    const int gi   = blockIdx.x * IPB + il;
    const int base = seg * 128;

    // ---- stage pos+ori into LDS ----
    for (int k = 0; k < NPART / NTHR; ++k) {
        const int j = k * NTHR + tid;
        ppos_s[j] = pos[j];
        pori_s[j] = ori[j];
    }
    __syncthreads();

    // ---- pairwise phase: 64 iters x 2 j's ----
    const float2 pi = ppos_s[gi];
    float nr = 0.f, sx = 0.f, sy = 0.f, oxs = 0.f, oys = 0.f;
    #pragma unroll 4
    for (int t = 0; t < 64; ++t) {
        const int k2 = (t + seg) & 63;    // stagger: 8 segs -> 8 bank groups
        const int j0 = base + 2 * k2;
        const float4 v = pp4[j0 >> 1];    // pos[j0], pos[j0+1]
        const float dx0 = v.x - pi.x, dy0 = v.y - pi.y;
        const float dx1 = v.z - pi.x, dy1 = v.w - pi.y;
        const float r20 = fmaf(dx0, dx0, dy0 * dy0);
        const float r21 = fmaf(dx1, dx1, dy1 * dy1);
        if (r20 <= RCAND2) {              // rare (incl. diagonal)
            const float2 uj = pori_s[j0];
            if (r20 <= RORC2) { oxs += uj.x; oys += uj.y; }   // inside_Ro
            if (r20 > 0.f) {
                if (r20 <= RR2) {
                    const float dt_ = fmaf(dx0, uj.x, dy0 * uj.y);
                    const float cr_ = fmaf(dy0, uj.x, -dx0 * uj.y);
                    if (!((dt_ <= 0.f) && (cr_ >= 0.f))) { nr += 1.f; sx += v.x; sy += v.y; }
                }
                const int slot = atomicAdd(&lcnt, 1);
                if (slot < CAP) lpairs[slot] = (gi << 12) | j0;
            }
        }
        if (r21 <= RCAND2) {
            const int j1 = j0 + 1;
            const float2 uj = pori_s[j1];
            if (r21 <= RORC2) { oxs += uj.x; oys += uj.y; }
            if (r21 > 0.f) {
                if (r21 <= RR2) {
                    const float dt_ = fmaf(dx1, uj.x, dy1 * uj.y);
                    const float cr_ = fmaf(dy1, uj.x, -dx1 * uj.y);
                    if (!((dt_ <= 0.f) && (cr_ >= 0.f))) { nr += 1.f; sx += v.z; sy += v.w; }
                }
                const int slot = atomicAdd(&lcnt, 1);
                if (slot < CAP) lpairs[slot] = (gi << 12) | j1;
            }
        }
    }
    __syncthreads();                       // lcnt final; LDS reads done
    sred[0 * NTHR + tid] = nr;
    sred[1 * NTHR + tid] = sx;
    sred[2 * NTHR + tid] = sy;
    sred[3 * NTHR + tid] = oxs;
    sred[4 * NTHR + tid] = oys;
    if (tid == 0) {
        const int n_l = (lcnt < CAP) ? lcnt : CAP;
        lbase = atomicAdd(counter, n_l);   // device-scope, reserve flat slots
        lcnt  = n_l;
    }
    __syncthreads();
    if (tid < 5 * IPB) {                   // same combine order as R1
        const int q = tid / IPB, ii = tid & (IPB - 1);
        float acc = 0.f;
        #pragma unroll
        for (int s = 0; s < 32; ++s) acc += sred[q * NTHR + ii + IPB * s];
        res[q][ii] = acc;
    }
    // ---- flush candidate list to flat global array ----
    for (int e = tid; e < lcnt; e += NTHR)
        pairs_g[lbase + e] = lpairs[e];
    __syncthreads();

    // ---- mean of all positions (n_a == N), same order as R1 ----
    float mx = 0.f, my = 0.f;
    for (int k = 0; k < NPART / NTHR; ++k) {
        const float2 v = ppos_s[k * NTHR + tid];
        mx += v.x; my += v.y;
    }
    sred[tid] = mx; sred[NTHR + tid] = my;
    __syncthreads();
    for (int s = NTHR / 2; s > 0; s >>= 1) {
        if (tid < s) { sred[tid] += sred[tid + s]; sred[NTHR + tid] += sred[NTHR + tid + s]; }
        __syncthreads();
    }
    const float cmx = sred[0]    * (1.f / NPART);
    const float cmy = sred[NTHR] * (1.f / NPART);

    // ---- per-i epilogue (8 threads) ----
    if (tid < IPB) {
        const int g2 = blockIdx.x * IPB + tid;
        const float2 p = ppos_s[g2];
        const float2 u = pori_s[g2];
        const float nrv = res[0][tid], sxv = res[1][tid], syv = res[2][tid];
        const float osx = res[3][tid], osy = res[4][tid];

        const float inv = 1.f / fmaxf(nrv, 1.f);
        const float sg  = (nrv > 0.f) ? 1.f : 0.f;
        const float Sx = sxv * inv - p.x * sg;
        const float Sy = syv * inv - p.y * sg;
        const float dxv = -Sx, dyv = -Sy;        // d = -S

        const float Psx = cmx - p.x;
        const float Psy = cmy - p.y;

        float sd, cd;
        sincosf(Deltas[0], &sd, &cd);
        const float Lx = Psx * cd - Psy * sd;    // Ps * exp(+i*Delta)
        const float Ly = Psx * sd + Psy * cd;
        const float Rx = Psx * cd + Psy * sd;    // Ps * exp(-i*Delta)
        const float Ry = Psy * cd - Psx * sd;

        const float no  = fmaxf(sqrtf(osx * osx + osy * osy + 1e-30f), EPSF);
        const float nl  = fmaxf(sqrtf(Lx * Lx + Ly * Ly + 1e-30f), EPSF);
        const float nrr = fmaxf(sqrtf(Rx * Rx + Ry * Ry + 1e-30f), EPSF);
        const float csl = (Lx * osx + Ly * osy) / (nl * no);
        const float csr = (Rx * osx + Ry * osy) / (nrr * no);
        const bool left = (csl >= csr);
        const float bx = left ? Lx : Rx;
        const float by = left ? Ly : Ry;

        float cx, cy;
        if (dxv != 0.f || dyv != 0.f)    { cx = dxv; cy = dyv; }
        else if (bx != 0.f || by != 0.f) { cx = bx;  cy = by;  }
        else                             { cx = 1.f; cy = 0.f; }

        const float dt_ = cx * u.x + cy * u.y;
        const float cr_ = cy * u.x - cx * u.y;
        const float sin_t = cr_ / sqrtf(dt_ * dt_ + cr_ * cr_);

        const float ang = C_ROT * sin_t + (rot_noise[g2] * C_RN1) * C_SQDT;
        float sa, ca;
        sincosf(ang, &sa, &ca);
        const float nux = u.x * ca - u.y * sa;
        const float nuy = u.x * sa + u.y * ca;

        const float2 tn = trans_noise[g2];
        const float tvx = C_TRV * u.x + ((tn.x * C_HALF) * C_SQ2T) * C_SQDT;
        const float tvy = C_TRV * u.y + ((tn.y * C_HALF) * C_SQ2T) * C_SQDT;

        out[1 * NPART + g2] = make_float2(nux, nuy);
        out[2 * NPART + g2] = make_float2(osx, osy);
        out[3 * NPART + g2] = make_float2(Lx, Ly);
        out[4 * NPART + g2] = make_float2(Rx, Ry);
        pA[g2] = make_float2(p.x + tvx, p.y + tvy);
    }
}

// ---------------------------------------------------------------------------
// Kernel 2: 3 collision passes, one block x 1024 thr. Pair codes preloaded
// ONCE into a statically-unrolled register array (predicated, sentinel -1);
// passes are pure LDS/VALU with independent ops + ds_add_f32 accumulation.
// ---------------------------------------------------------------------------
__global__ __launch_bounds__(1024) void collide_sparse(
        const float2* __restrict__ pA, const int* __restrict__ counter,
        const int* __restrict__ pairs_g, float2* __restrict__ out0) {
    __shared__ float2 ppos[NPART];        // 32 KB
    __shared__ float  macx[NPART];        // 16 KB
    __shared__ float  macy[NPART];        // 16 KB

    const int tid = threadIdx.x;
    for (int k = 0; k < NPART / 1024; ++k)
        ppos[k * 1024 + tid] = pA[k * 1024 + tid];
    int nc = *counter;
    nc = (nc < KREG * 1024) ? nc : KREG * 1024;

    int pk[KREG];                         // register-resident pair codes
    #pragma unroll
    for (int k = 0; k < KREG; ++k) {
        const int e = tid + k * 1024;     // coalesced
        pk[k] = (e < nc) ? pairs_g[e] : -1;
    }
    __syncthreads();

    for (int pass = 0; pass < 3; ++pass) {
        for (int k = 0; k < NPART / 1024; ++k) {
            macx[k * 1024 + tid] = 0.f;
            macy[k * 1024 + tid] = 0.f;
        }
        __syncthreads();
        #pragma unroll
        for (int k = 0; k < KREG; ++k) {
            if (pk[k] >= 0) {
                const int i = pk[k] >> 12;
                const int j = pk[k] & (NPART - 1);
                const float2 pi = ppos[i];
                const float2 pj = ppos[j];
                const float dx = pj.x - pi.x, dy = pj.y - pi.y;
                const float r2 = fmaf(dx, dx, dy * dy);
                if (r2 <= TWORC2 && r2 > 0.f) {
                    const float ab = sqrtf(r2);
                    const float s = (C21RC - ab) * 0.5f / ab;
                    atomicAdd(&macx[i], dx * s);   // ds_add_f32
                    atomicAdd(&macy[i], dy * s);
                }
            }
        }
        __syncthreads();
        for (int k = 0; k < NPART / 1024; ++k) {
            const int i = k * 1024 + tid;
            ppos[i].x -= macx[i];
            ppos[i].y -= macy[i];
        }
        __syncthreads();
    }
    for (int k = 0; k < NPART / 1024; ++k)
        out0[k * 1024 + tid] = ppos[k * 1024 + tid];
}

extern "C" void kernel_launch(void* const* d_in, const int* in_sizes, int n_in,
                              void* d_out, int out_size, void* d_ws, size_t ws_size,
                              hipStream_t stream) {
    const float2* pos = (const float2*)d_in[0];
    const float2* ori = (const float2*)d_in[1];
    const float*  del = (const float*)d_in[2];
    const float*  rn  = (const float*)d_in[3];
    const float2* tn  = (const float2*)d_in[4];

    float2* pA      = (float2*)d_ws;                                // 32 KB
    int*    counter = (int*)((char*)d_ws + NPART * sizeof(float2)); // 4 B (+pad)
    int*    pairs   = counter + 16;                                 // 1 MB
    float2* o2      = (float2*)d_out;                               // [5][N] float2

    zero_counter<<<dim3(1), dim3(1), 0, stream>>>(counter);
    fused_main<<<dim3(NBLK), dim3(NTHR), 0, stream>>>(pos, ori, del, rn, tn,
                                                      o2, pA, counter, pairs);
    collide_sparse<<<dim3(1), dim3(1024), 0, stream>>>(pA, counter, pairs, o2);
}

// Round 8
// 98.487 us; speedup vs baseline: 2.8942x; 1.0469x over previous
//
#include <hip/hip_runtime.h>
#include <math.h>

#define NPART 4096
#define NBLK  512
#define NTHR  256
#define IPB   8     // particles (i) per block in kernel 1
#define CAP   512   // max candidate pairs per block (i<j only; expected ~26)
#define FCAP  16384 // flat list capacity in collide (expected ~13.5K)

// Constants, rounded exactly as the reference's weak-typed doubles -> f32
constexpr float RORC   = (float)(2.5e-5 + 3.15e-6);    // RO + RC
constexpr float RORC2  = RORC * RORC;
constexpr float RRF    = 8e-6f;                        // RR
constexpr float RR2    = RRF * RRF;
constexpr float TWORC  = (float)(2.0 * 3.15e-6);       // 2*RC
constexpr float TWORC2 = TWORC * TWORC;
constexpr float C21RC  = (float)(2.1 * 3.15e-6);       // 2.1*RC
constexpr float RCAND2 = 1.6e-9f;                      // (4e-5)^2 > RORC^2
constexpr float C_ROT  = (float)(0.2 * 25.0 * 0.0028); // dt*Gamma*DR
constexpr float C_RN1  = (float)0.07483314773547883;   // f32(sqrt(2*DR))
constexpr float C_SQDT = (float)0.4472135954999579;    // f32(sqrt(dt))
constexpr float C_TRV  = (float)(0.2 * 5e-7);          // dt*velocity
constexpr float C_HALF = (float)0.7071067811865476;    // f32(sqrt(0.5))
constexpr float C_SQ2T = (float)1.6733200530681511e-07;// f32(sqrt(2*DT_TRANS))
constexpr float EPSF   = 1e-14f;

// ---------------------------------------------------------------------------
// Kernel 1: pair sums + per-block mean + epilogue + per-block candidate list
// (i<j only, fixed region per block -> NO global counter, no zero kernel).
// 512 blocks x 256 thr; block owns 8 i's, 32 j-segs of 128. Hot loop touches
// only positions (2 j's per ds_read_b128); all rare work inside RCAND2 branch.
// ---------------------------------------------------------------------------
__global__ __launch_bounds__(NTHR) void fused_main(
        const float2* __restrict__ pos, const float2* __restrict__ ori,
        const float* __restrict__ Deltas, const float* __restrict__ rot_noise,
        const float2* __restrict__ trans_noise,
        float2* __restrict__ out, float2* __restrict__ pA,
        int* __restrict__ counts_g, int* __restrict__ pairs_g) {
    __shared__ float4 pp4[NPART / 2];     // 32 KB, positions as float2[NPART]
    __shared__ float2 pori_s[NPART];      // 32 KB, orientations
    __shared__ float  sred[5 * NTHR];     // 5 KB
    __shared__ float  res[5][IPB];
    __shared__ int    lcnt;
    __shared__ int    lpairs[CAP];        // 2 KB
    float2* ppos_s = (float2*)pp4;

    const int tid  = threadIdx.x;
    if (tid == 0) lcnt = 0;
    const int il   = tid & (IPB - 1);
    const int seg  = tid / IPB;           // 0..31
    const int gi   = blockIdx.x * IPB + il;
    const int base = seg * 128;

    // ---- stage pos+ori into LDS ----
    for (int k = 0; k < NPART / NTHR; ++k) {
        const int j = k * NTHR + tid;
        ppos_s[j] = pos[j];
        pori_s[j] = ori[j];
    }
    __syncthreads();

    // ---- pairwise phase: 64 iters x 2 j's ----
    const float2 pi = ppos_s[gi];
    float nr = 0.f, sx = 0.f, sy = 0.f, oxs = 0.f, oys = 0.f;
    #pragma unroll 4
    for (int t = 0; t < 64; ++t) {
        const int k2 = (t + seg) & 63;    // stagger: 8 segs -> 8 bank groups
        const int j0 = base + 2 * k2;
        const float4 v = pp4[j0 >> 1];    // pos[j0], pos[j0+1]
        const float dx0 = v.x - pi.x, dy0 = v.y - pi.y;
        const float dx1 = v.z - pi.x, dy1 = v.w - pi.y;
        const float r20 = fmaf(dx0, dx0, dy0 * dy0);
        const float r21 = fmaf(dx1, dx1, dy1 * dy1);
        if (r20 <= RCAND2) {              // rare (incl. diagonal)
            const float2 uj = pori_s[j0];
            if (r20 <= RORC2) { oxs += uj.x; oys += uj.y; }   // inside_Ro
            if (r20 > 0.f) {
                if (r20 <= RR2) {
                    const float dt_ = fmaf(dx0, uj.x, dy0 * uj.y);
                    const float cr_ = fmaf(dy0, uj.x, -dx0 * uj.y);
                    if (!((dt_ <= 0.f) && (cr_ >= 0.f))) { nr += 1.f; sx += v.x; sy += v.y; }
                }
                if (gi < j0) {            // unordered pair, appended once
                    const int slot = atomicAdd(&lcnt, 1);
                    if (slot < CAP) lpairs[slot] = (gi << 12) | j0;
                }
            }
        }
        if (r21 <= RCAND2) {
            const int j1 = j0 + 1;
            const float2 uj = pori_s[j1];
            if (r21 <= RORC2) { oxs += uj.x; oys += uj.y; }
            if (r21 > 0.f) {
                if (r21 <= RR2) {
                    const float dt_ = fmaf(dx1, uj.x, dy1 * uj.y);
                    const float cr_ = fmaf(dy1, uj.x, -dx1 * uj.y);
                    if (!((dt_ <= 0.f) && (cr_ >= 0.f))) { nr += 1.f; sx += v.z; sy += v.w; }
                }
                if (gi < j1) {
                    const int slot = atomicAdd(&lcnt, 1);
                    if (slot < CAP) lpairs[slot] = (gi << 12) | j1;
                }
            }
        }
    }
    __syncthreads();                       // lcnt final; LDS reads done
    sred[0 * NTHR + tid] = nr;
    sred[1 * NTHR + tid] = sx;
    sred[2 * NTHR + tid] = sy;
    sred[3 * NTHR + tid] = oxs;
    sred[4 * NTHR + tid] = oys;
    __syncthreads();
    if (tid < 5 * IPB) {                   // same combine order as R1
        const int q = tid / IPB, ii = tid & (IPB - 1);
        float acc = 0.f;
        #pragma unroll
        for (int s = 0; s < 32; ++s) acc += sred[q * NTHR + ii + IPB * s];
        res[q][ii] = acc;
    }
    // ---- flush per-block candidate list to its fixed region ----
    {
        const int n_l = (lcnt < CAP) ? lcnt : CAP;
        for (int e = tid; e < n_l; e += NTHR)
            pairs_g[blockIdx.x * CAP + e] = lpairs[e];
        if (tid == 0) counts_g[blockIdx.x] = n_l;
    }
    __syncthreads();

    // ---- mean of all positions (n_a == N), same order as R1 ----
    float mx = 0.f, my = 0.f;
    for (int k = 0; k < NPART / NTHR; ++k) {
        const float2 v = ppos_s[k * NTHR + tid];
        mx += v.x; my += v.y;
    }
    sred[tid] = mx; sred[NTHR + tid] = my;
    __syncthreads();
    for (int s = NTHR / 2; s > 0; s >>= 1) {
        if (tid < s) { sred[tid] += sred[tid + s]; sred[NTHR + tid] += sred[NTHR + tid + s]; }
        __syncthreads();
    }
    const float cmx = sred[0]    * (1.f / NPART);
    const float cmy = sred[NTHR] * (1.f / NPART);

    // ---- per-i epilogue (8 threads) ----
    if (tid < IPB) {
        const int g2 = blockIdx.x * IPB + tid;
        const float2 p = ppos_s[g2];
        const float2 u = pori_s[g2];
        const float nrv = res[0][tid], sxv = res[1][tid], syv = res[2][tid];
        const float osx = res[3][tid], osy = res[4][tid];

        const float inv = 1.f / fmaxf(nrv, 1.f);
        const float sg  = (nrv > 0.f) ? 1.f : 0.f;
        const float Sx = sxv * inv - p.x * sg;
        const float Sy = syv * inv - p.y * sg;
        const float dxv = -Sx, dyv = -Sy;        // d = -S

        const float Psx = cmx - p.x;
        const float Psy = cmy - p.y;

        float sd, cd;
        sincosf(Deltas[0], &sd, &cd);
        const float Lx = Psx * cd - Psy * sd;    // Ps * exp(+i*Delta)
        const float Ly = Psx * sd + Psy * cd;
        const float Rx = Psx * cd + Psy * sd;    // Ps * exp(-i*Delta)
        const float Ry = Psy * cd - Psx * sd;

        const float no  = fmaxf(sqrtf(osx * osx + osy * osy + 1e-30f), EPSF);
        const float nl  = fmaxf(sqrtf(Lx * Lx + Ly * Ly + 1e-30f), EPSF);
        const float nrr = fmaxf(sqrtf(Rx * Rx + Ry * Ry + 1e-30f), EPSF);
        const float csl = (Lx * osx + Ly * osy) / (nl * no);
        const float csr = (Rx * osx + Ry * osy) / (nrr * no);
        const bool left = (csl >= csr);
        const float bx = left ? Lx : Rx;
        const float by = left ? Ly : Ry;

        float cx, cy;
        if (dxv != 0.f || dyv != 0.f)    { cx = dxv; cy = dyv; }
        else if (bx != 0.f || by != 0.f) { cx = bx;  cy = by;  }
        else                             { cx = 1.f; cy = 0.f; }

        const float dt_ = cx * u.x + cy * u.y;
        const float cr_ = cy * u.x - cx * u.y;
        const float sin_t = cr_ / sqrtf(dt_ * dt_ + cr_ * cr_);

        const float ang = C_ROT * sin_t + (rot_noise[g2] * C_RN1) * C_SQDT;
        float sa, ca;
        sincosf(ang, &sa, &ca);
        const float nux = u.x * ca - u.y * sa;
        const float nuy = u.x * sa + u.y * ca;

        const float2 tn = trans_noise[g2];
        const float tvx = C_TRV * u.x + ((tn.x * C_HALF) * C_SQ2T) * C_SQDT;
        const float tvy = C_TRV * u.y + ((tn.y * C_HALF) * C_SQ2T) * C_SQDT;

        out[1 * NPART + g2] = make_float2(nux, nuy);
        out[2 * NPART + g2] = make_float2(osx, osy);
        out[3 * NPART + g2] = make_float2(Lx, Ly);
        out[4 * NPART + g2] = make_float2(Rx, Ry);
        pA[g2] = make_float2(p.x + tvx, p.y + tvy);
    }
}

// ---------------------------------------------------------------------------
// Kernel 2: 3 collision passes, one block x 1024 thr. Prefix-scan the 512
// per-block counts, compact pairs to a flat LDS list once, then 3 passes of
// direct symmetric atomic updates on LDS positions (Gauss-Seidel relaxation;
// deviation from the reference's Jacobi passes is bounded by the total move
// magnitude ~1e-5, vs threshold 0.1325).
// ---------------------------------------------------------------------------
__global__ __launch_bounds__(1024) void collide_sparse(
        const float2* __restrict__ pA, const int* __restrict__ counts_g,
        const int* __restrict__ pairs_g, float2* __restrict__ out0) {
    __shared__ float2 ppos[NPART];        // 32 KB
    __shared__ int    flat[FCAP];         // 64 KB
    __shared__ int    scan[NBLK];         // 2 KB

    const int tid = threadIdx.x;
    for (int k = 0; k < NPART / 1024; ++k)
        ppos[k * 1024 + tid] = pA[k * 1024 + tid];

    int c_own = 0;
    if (tid < NBLK) {
        c_own = counts_g[tid];
        scan[tid] = c_own;
    }
    __syncthreads();
    // Hillis-Steele inclusive scan over 512 counts
    for (int off = 1; off < NBLK; off <<= 1) {
        int v = 0;
        if (tid < NBLK) {
            v = scan[tid];
            if (tid >= off) v += scan[tid - off];
        }
        __syncthreads();
        if (tid < NBLK) scan[tid] = v;
        __syncthreads();
    }
    const int total_raw = scan[NBLK - 1];
    const int total = (total_raw < FCAP) ? total_raw : FCAP;
    // compact: thread b copies its block's entries to flat[offset..]
    if (tid < NBLK) {
        const int off = scan[tid] - c_own;
        for (int e = 0; e < c_own; ++e) {
            const int idx = off + e;
            if (idx < FCAP) flat[idx] = pairs_g[tid * CAP + e];
        }
    }
    __syncthreads();

    for (int pass = 0; pass < 3; ++pass) {
        for (int e = tid; e < total; e += 1024) {
            const int code = flat[e];
            const int i = code >> 12;
            const int j = code & (NPART - 1);
            const float2 pi = ppos[i];
            const float2 pj = ppos[j];
            const float dx = pj.x - pi.x, dy = pj.y - pi.y;
            const float r2 = fmaf(dx, dx, dy * dy);
            if (r2 <= TWORC2 && r2 > 0.f) {
                const float ab = sqrtf(r2);
                const float s = (C21RC - ab) * 0.5f / ab;
                const float mx = dx * s, my = dy * s;
                atomicAdd(&ppos[i].x, -mx);   // ds_add_f32
                atomicAdd(&ppos[i].y, -my);
                atomicAdd(&ppos[j].x,  mx);   // antisymmetric partner
                atomicAdd(&ppos[j].y,  my);
            }
        }
        __syncthreads();
    }
    for (int k = 0; k < NPART / 1024; ++k)
        out0[k * 1024 + tid] = ppos[k * 1024 + tid];
}

extern "C" void kernel_launch(void* const* d_in, const int* in_sizes, int n_in,
                              void* d_out, int out_size, void* d_ws, size_t ws_size,
                              hipStream_t stream) {
    const float2* pos = (const float2*)d_in[0];
    const float2* ori = (const float2*)d_in[1];
    const float*  del = (const float*)d_in[2];
    const float*  rn  = (const float*)d_in[3];
    const float2* tn  = (const float2*)d_in[4];

    float2* pA     = (float2*)d_ws;                                // 32 KB
    int*    counts = (int*)((char*)d_ws + NPART * sizeof(float2)); // 2 KB
    int*    pairs  = counts + NBLK;                                // 1 MB
    float2* o2     = (float2*)d_out;                               // [5][N] float2

    fused_main<<<dim3(NBLK), dim3(NTHR), 0, stream>>>(pos, ori, del, rn, tn,
                                                      o2, pA, counts, pairs);
    collide_sparse<<<dim3(1), dim3(1024), 0, stream>>>(pA, counts, pairs, o2);
}